// Round 11
// baseline (174.240 us; speedup 1.0000x reference)
//
#include <hip/hip_runtime.h>

#define NCLS 13
#define DIM  256
// (1/0.07) * log2(e): folds temperature AND exp2-domain conversion into A's scale
#define SCL  20.609929155f

typedef short bf16x8 __attribute__((ext_vector_type(8)));
typedef float f32x4  __attribute__((ext_vector_type(4)));

__device__ __forceinline__ float bf2f(unsigned u16){
  union { unsigned u; float f; } v; v.u = u16 << 16; return v.f;
}
__device__ __forceinline__ unsigned f2bf(float f){
  union { float f; unsigned u; } v; v.f = f;
  unsigned r = v.u + 0x7fffu + ((v.u >> 16) & 1u);
  return r >> 16;
}

__device__ __forceinline__ void gload_lds16(const void* g, void* l){
  __builtin_amdgcn_global_load_lds((const __attribute__((address_space(1))) unsigned*)g,
                                   (__attribute__((address_space(3))) unsigned*)l, 16, 0, 0);
}

// ---------------- prep kernels ----------------

__global__ void k_zero(int* counts, unsigned* packLab, double* accum, int n, int np){
  int i = blockIdx.x*blockDim.x + threadIdx.x;
  if (i < n)  counts[i] = 0;
  if (i < np) packLab[i] = 0u;
  if (i == 0) *accum = 0.0;
}

__global__ void k_hist(const int* __restrict__ idx, const int* __restrict__ lab,
                       int* __restrict__ counts, int n){
  int i = blockIdx.x*blockDim.x + threadIdx.x;
  if (i < n) atomicAdd(&counts[idx[i]*NCLS + lab[i]], 1);
}

// one block, M threads. argmax labels + label-sorted permutation + nibble-packed
// column labels for 64-col chunks: packLab[(pos>>6)*16 + (pos&15)], nibble (pos>>4)&3.
__global__ void k_label_perm(const int* __restrict__ counts, int* __restrict__ spLabel,
                             int* __restrict__ newpos, unsigned* __restrict__ packLab){
  int m = threadIdx.x;
  int best = 0; int bc = counts[m*NCLS];
  #pragma unroll
  for (int c = 1; c < NCLS; ++c){ int v = counts[m*NCLS+c]; if (v > bc){ bc = v; best = c; } }
  spLabel[m] = best;

  __shared__ int waveCnt[16][NCLS];
  __shared__ int waveOff[16][NCLS];
  __shared__ int classTot[NCLS];
  __shared__ int classBase[NCLS];
  int lane = m & 63, wid = m >> 6;
  int nw = blockDim.x >> 6;
  int rankInWave = 0;
  unsigned long long below = (1ull << lane) - 1ull;
  for (int c = 0; c < NCLS; ++c){
    unsigned long long bal = __ballot(best == c);
    if (best == c) rankInWave = __popcll(bal & below);
    if (lane == 0) waveCnt[wid][c] = __popcll(bal);
  }
  __syncthreads();
  if (m < NCLS){
    int c = m, s = 0;
    for (int w = 0; w < nw; ++w){ waveOff[w][c] = s; s += waveCnt[w][c]; }
    classTot[c] = s;
  }
  __syncthreads();
  if (m == 0){ int s = 0; for (int c = 0; c < NCLS; ++c){ classBase[c] = s; s += classTot[c]; } }
  __syncthreads();
  int pos = classBase[best] + waveOff[wid][best] + rankInWave;
  newpos[m] = pos;
  atomicOr(&packLab[(pos >> 6)*16 + (pos & 15)], (unsigned)best << (((pos >> 4) & 3)*4));
}

// one wave per superpoint row: normalize, write bf16 in original and permuted order
__global__ void k_norm_sp(const float* __restrict__ sp, const int* __restrict__ newpos,
                          unsigned short* __restrict__ spnO, unsigned short* __restrict__ spnP){
  int m = blockIdx.x, lane = threadIdx.x;
  const float4 v = *(const float4*)(sp + (size_t)m*DIM + lane*4);
  float ss = v.x*v.x + v.y*v.y + v.z*v.z + v.w*v.w;
  #pragma unroll
  for (int o = 1; o < 64; o <<= 1) ss += __shfl_xor(ss, o);
  float rn = 1.0f / sqrtf(ss + 1e-12f);
  uint2 w;
  w.x = f2bf(v.x*rn) | (f2bf(v.y*rn) << 16);
  w.y = f2bf(v.z*rn) | (f2bf(v.w*rn) << 16);
  *(uint2*)(spnO + (size_t)m*DIM + lane*4) = w;
  int p = newpos[m];
  *(uint2*)(spnP + (size_t)p*DIM + lane*4) = w;
}

// ---------------- main fused GEMM ----------------
// 256 threads = 4 waves; wave owns 64 rows x ALL 1024 cols. BM=256, grid 512.
// A: in registers a[4][8] = 128 VGPR (this is the whole point: LDS-read bytes
// per output = K*2B/rows_per_wave -> 64 rows/wave HALVES per-CU LDS traffic
// vs R9/R10's 32). 256-thread blocks because the 512-thread allocator clamps
// at 128 VGPR (R8: 319 MB spill); at 256 threads it granted 172 spill-free (R6).
// B: 16 chunks of 64 cols x K=256 (32 KB), double-buffered, depth-2 prefetch,
// counted vmcnt(8) + raw s_barrier. No A-LDS staging (pass2 reloads frag bytes
// from L2-hot rp) -> B DMA starts at kernel entry, overlapping the prologue;
// no __syncthreads anywhere.

#define SBAR()   __builtin_amdgcn_s_barrier()
#define SFENCE() __builtin_amdgcn_sched_barrier(0)

__device__ __forceinline__ void stageB(const unsigned short* __restrict__ spnP,
                                       void* buf, int c, int tid){
  const int wid = tid >> 6;
  #pragma unroll
  for (int i = 0; i < 8; ++i){
    const int d    = i*4096 + tid*16;      // linear dst byte in 32 KB chunk
    const int colp = d >> 9;               // 512 B per column (256 k * 2B)
    const int x    = d & 511;
    const char* src = (const char*)spnP + (size_t)(c*64 + colp)*512 + (x ^ ((colp & 7) << 4));
    char* dst = (char*)buf + i*4096 + wid*1024;   // wave-uniform; HW adds lane*16
    gload_lds16(src, dst);
  }
}

__attribute__((amdgpu_waves_per_eu(1, 2)))
__launch_bounds__(256)
__global__ void k_main(const float* __restrict__ rp, const int* __restrict__ rawIdx,
                       const unsigned short* __restrict__ spnO, const unsigned short* __restrict__ spnP,
                       const unsigned* __restrict__ packLab, const int* __restrict__ spLabel,
                       double* __restrict__ accum, int M){
  __shared__ __align__(16) unsigned short Bsh[2][64*256];  // 64 KB dbuf
  __shared__ float    posLt[256];
  __shared__ float    normS[256];
  __shared__ int      posLb[256];
  __shared__ unsigned cpLds[256];

  const int tid  = threadIdx.x;
  const int lane = tid & 63, wid = tid >> 6;
  const int l15  = lane & 15, l4 = lane >> 4;
  const int rowBlock = blockIdx.x * 256;

  // B chunks 0/1 in flight immediately (overlap entire prologue)
  stageB(spnP, &Bsh[0][0], 0, tid);
  stageB(spnP, &Bsh[1][0], 1, tid);

  cpLds[tid] = packLab[tid];                       // 16 chunks x 16 words
  const int sidxOwn = rawIdx[rowBlock + tid];      // lane (tid&63) of wave holds row tid
  posLb[tid] = spLabel[sidxOwn];

  // ---- pass 1: norms + positive logits; 16-lane split, 4 rows/iter ----
  // lane(l4,l15): row wid*64 + it*4 + l4, elems [l15*16, +16)
  for (int it = 0; it < 16; ++it){
    const int rl  = it*4 + l4;
    const int row = wid*64 + rl;
    const float* rpp = rp + (size_t)(rowBlock + row)*DIM + l15*16;
    const float4 v0 = *(const float4*)(rpp);
    const float4 v1 = *(const float4*)(rpp + 4);
    const float4 v2 = *(const float4*)(rpp + 8);
    const float4 v3 = *(const float4*)(rpp + 12);
    const int sidx = __shfl(sidxOwn, rl);          // row rl held by lane rl of this wave
    const uint4 s0 = *(const uint4*)(spnO + (size_t)sidx*DIM + l15*16);
    const uint4 s1 = *(const uint4*)(spnO + (size_t)sidx*DIM + l15*16 + 8);
    float ss = v0.x*v0.x + v0.y*v0.y + v0.z*v0.z + v0.w*v0.w
             + v1.x*v1.x + v1.y*v1.y + v1.z*v1.z + v1.w*v1.w
             + v2.x*v2.x + v2.y*v2.y + v2.z*v2.z + v2.w*v2.w
             + v3.x*v3.x + v3.y*v3.y + v3.z*v3.z + v3.w*v3.w;
    float dr =
      v0.x*bf2f(s0.x & 0xffff) + v0.y*bf2f(s0.x >> 16) +
      v0.z*bf2f(s0.y & 0xffff) + v0.w*bf2f(s0.y >> 16) +
      v1.x*bf2f(s0.z & 0xffff) + v1.y*bf2f(s0.z >> 16) +
      v1.z*bf2f(s0.w & 0xffff) + v1.w*bf2f(s0.w >> 16) +
      v2.x*bf2f(s1.x & 0xffff) + v2.y*bf2f(s1.x >> 16) +
      v2.z*bf2f(s1.y & 0xffff) + v2.w*bf2f(s1.y >> 16) +
      v3.x*bf2f(s1.z & 0xffff) + v3.y*bf2f(s1.z >> 16) +
      v3.z*bf2f(s1.w & 0xffff) + v3.w*bf2f(s1.w >> 16);
    ss += __shfl_xor(ss, 1); dr += __shfl_xor(dr, 1);
    ss += __shfl_xor(ss, 2); dr += __shfl_xor(dr, 2);
    ss += __shfl_xor(ss, 4); dr += __shfl_xor(dr, 4);
    ss += __shfl_xor(ss, 8); dr += __shfl_xor(dr, 8);
    const float rn = SCL / sqrtf(ss + 1e-12f);
    if (l15 == 0){ normS[row] = rn; posLt[row] = rn * dr; }
  }

  // ---- pass 2: A frags direct from rp (L2-hot), scaled+packed in regs ----
  bf16x8 a[4][8];
  #pragma unroll
  for (int rt = 0; rt < 4; ++rt){
    const int row = wid*64 + rt*16 + l15;
    const float rn = normS[row];                   // same-wave LDS write->read
    const float* base = rp + (size_t)(rowBlock + row)*DIM;
    #pragma unroll
    for (int kf = 0; kf < 8; ++kf){
      const float4 u0 = *(const float4*)(base + kf*32 + l4*8);
      const float4 u1 = *(const float4*)(base + kf*32 + l4*8 + 4);
      bf16x8 f;
      f[0] = (short)f2bf(u0.x*rn); f[1] = (short)f2bf(u0.y*rn);
      f[2] = (short)f2bf(u0.z*rn); f[3] = (short)f2bf(u0.w*rn);
      f[4] = (short)f2bf(u1.x*rn); f[5] = (short)f2bf(u1.y*rn);
      f[6] = (short)f2bf(u1.z*rn); f[7] = (short)f2bf(u1.w*rn);
      a[rt][kf] = f;
    }
  }

  // row labels nibble-packed: ri = rf*4+e -> wave-local row rf*16 + l4*4 + e
  unsigned Lp0 = 0, Lp1 = 0;
  #pragma unroll
  for (int rf = 0; rf < 4; ++rf)
    #pragma unroll
    for (int e = 0; e < 4; ++e){
      unsigned lb = (unsigned)posLb[wid*64 + rf*16 + l4*4 + e];
      int ri = rf*4 + e;
      if (rf < 2) Lp0 |= lb << (ri*4);
      else        Lp1 |= lb << ((ri - 8)*4);
    }

  float sumT[16], sumO[16];
  #pragma unroll
  for (int i = 0; i < 16; ++i){ sumT[i] = 0.f; sumO[i] = 0.f; }

  const int nChunks = M >> 6;          // 16
  for (int c = 0; c < nChunks; ++c){
    const unsigned cpack = cpLds[c*16 + l15];
    if (c < nChunks - 1) asm volatile("s_waitcnt vmcnt(8)" ::: "memory");
    else                 asm volatile("s_waitcnt vmcnt(0)" ::: "memory");
    SFENCE(); SBAR(); SFENCE();

    const char* Bp = (const char*)&Bsh[c & 1][0];
    #pragma unroll
    for (int cf = 0; cf < 4; ++cf){
      const int colp = cf*16 + l15;
      const int swz  = (l15 & 7) << 4;
      bf16x8 b[8];
      #pragma unroll
      for (int kq = 0; kq < 8; ++kq)
        b[kq] = *(const bf16x8*)(Bp + colp*512 + ((kq*64 + l4*16) ^ swz));
      f32x4 acc[4];
      #pragma unroll
      for (int rt = 0; rt < 4; ++rt) acc[rt] = (f32x4){0.f,0.f,0.f,0.f};
      #pragma unroll
      for (int kq = 0; kq < 8; ++kq)
        #pragma unroll
        for (int rt = 0; rt < 4; ++rt)
          acc[rt] = __builtin_amdgcn_mfma_f32_16x16x32_bf16(a[rt][kq], b[kq], acc[rt], 0, 0, 0);
      const unsigned colLab = (cpack >> (cf*4)) & 15u;
      #pragma unroll
      for (int rt = 0; rt < 4; ++rt)
        #pragma unroll
        for (int e = 0; e < 4; ++e){
          const float ev = __builtin_amdgcn_exp2f(acc[rt][e]);
          const int ri = rt*4 + e;
          const unsigned lr = ((rt < 2 ? Lp0 : Lp1) >> ((ri & 7)*4)) & 15u;
          sumT[ri] += ev;
          sumO[ri] += (lr == colLab) ? ev : 0.f;
        }
    }
    SFENCE(); SBAR(); SFENCE();
    if (c + 2 < nChunks) stageB(spnP, &Bsh[c & 1][0], c + 2, tid);
  }

  // reduce over the 16 l15-lanes sharing each row
  #pragma unroll
  for (int i = 0; i < 16; ++i){
    #pragma unroll
    for (int o = 1; o < 16; o <<= 1){
      sumT[i] += __shfl_xor(sumT[i], o);
      sumO[i] += __shfl_xor(sumO[i], o);
    }
  }

  // finish in log2 domain: loss_i = ln2 * (log2(den) - pl2); ln2 folded into k_final
  float part = 0.f;
  #pragma unroll
  for (int rf = 0; rf < 4; ++rf)
    #pragma unroll
    for (int e = 0; e < 4; ++e){
      const float pl  = posLt[wid*64 + rf*16 + l4*4 + e];
      const float ep  = __builtin_amdgcn_exp2f(pl);
      const float den = ep + (sumT[rf*4+e] - sumO[rf*4+e]) + 1e-8f;
      part += __builtin_amdgcn_logf(den) - pl;   // v_log_f32 = log2
    }
  part = (l15 == 0) ? part : 0.f;
  #pragma unroll
  for (int o = 1; o < 64; o <<= 1) part += __shfl_xor(part, o);
  if (lane == 0) atomicAdd(accum, (double)part);
}

__global__ void k_final(const double* __restrict__ accum, float* __restrict__ out, int N){
  out[0] = (float)((*accum / (double)N) * (0.07 * 0.6931471805599453));
}

// ---------------- launch ----------------

extern "C" void kernel_launch(void* const* d_in, const int* in_sizes, int n_in,
                              void* d_out, int out_size, void* d_ws, size_t ws_size,
                              hipStream_t stream){
  const float* sp  = (const float*)d_in[0];
  const float* rp  = (const float*)d_in[1];
  const int*   idx = (const int*)d_in[2];
  const int*   lab = (const int*)d_in[3];
  const int M = in_sizes[0] / DIM;     // 1024
  const int N = in_sizes[2];           // 131072

  char* ws = (char*)d_ws;
  size_t off = 0;
  auto alloc = [&](size_t bytes){ void* p = ws + off; off = (off + bytes + 255) & ~(size_t)255; return p; };
  int*      counts  = (int*)     alloc((size_t)M * NCLS * 4);
  int*      spLabel = (int*)     alloc((size_t)M * 4);
  int*      newpos  = (int*)     alloc((size_t)M * 4);
  unsigned* packLab = (unsigned*)alloc((size_t)(M/64) * 16 * 4);
  double*   accum   = (double*)  alloc(16);
  unsigned short* spnO = (unsigned short*)alloc((size_t)M * DIM * 2);
  unsigned short* spnP = (unsigned short*)alloc((size_t)M * DIM * 2);

  k_zero<<<(M*NCLS + 255)/256, 256, 0, stream>>>(counts, packLab, accum, M*NCLS, (M/64)*16);
  k_hist<<<(N + 255)/256, 256, 0, stream>>>(idx, lab, counts, N);
  k_label_perm<<<1, M, 0, stream>>>(counts, spLabel, newpos, packLab);
  k_norm_sp<<<M, 64, 0, stream>>>(sp, newpos, spnO, spnP);
  k_main<<<N/256, 256, 0, stream>>>(rp, idx, spnO, spnP, packLab, spLabel, accum, M);
  k_final<<<1, 1, 0, stream>>>(accum, (float*)d_out, N);
}

// Round 12
// 145.770 us; speedup vs baseline: 1.1953x; 1.1953x over previous
//
#include <hip/hip_runtime.h>

#define NCLS 13
#define DIM  256
// (1/0.07) * log2(e): folds temperature AND exp2-domain conversion into A's scale
#define SCL  20.609929155f

typedef float f32x4 __attribute__((ext_vector_type(4)));

__device__ __forceinline__ float bf2f(unsigned u16){
  union { unsigned u; float f; } v; v.u = u16 << 16; return v.f;
}
__device__ __forceinline__ unsigned f2bf(float f){
  union { float f; unsigned u; } v; v.f = f;
  unsigned r = v.u + 0x7fffu + ((v.u >> 16) & 1u);
  return r >> 16;
}
// pack 4 floats -> 4 fp8 e4m3 bytes
__device__ __forceinline__ unsigned pk4fp8(float f0, float f1, float f2, float f3){
  unsigned u = __builtin_amdgcn_cvt_pk_fp8_f32(f0, f1, 0, false);
  return (unsigned)__builtin_amdgcn_cvt_pk_fp8_f32(f2, f3, u, true);
}

__device__ __forceinline__ void gload_lds16(const void* g, void* l){
  __builtin_amdgcn_global_load_lds((const __attribute__((address_space(1))) unsigned*)g,
                                   (__attribute__((address_space(3))) unsigned*)l, 16, 0, 0);
}

// ---------------- prep kernels ----------------

__global__ void k_zero(int* counts, unsigned* packLab, double* accum, int n, int np){
  int i = blockIdx.x*blockDim.x + threadIdx.x;
  if (i < n)  counts[i] = 0;
  if (i < np) packLab[i] = 0u;
  if (i == 0) *accum = 0.0;
}

__global__ void k_hist(const int* __restrict__ idx, const int* __restrict__ lab,
                       int* __restrict__ counts, int n){
  int i = blockIdx.x*blockDim.x + threadIdx.x;
  if (i < n) atomicAdd(&counts[idx[i]*NCLS + lab[i]], 1);
}

// one block, M threads. argmax labels + label-sorted permutation + nibble-packed
// column labels for 64-col groups: packLab[(pos>>6)*16 + (pos&15)], nibble (pos>>4)&3.
__global__ void k_label_perm(const int* __restrict__ counts, int* __restrict__ spLabel,
                             int* __restrict__ newpos, unsigned* __restrict__ packLab){
  int m = threadIdx.x;
  int best = 0; int bc = counts[m*NCLS];
  #pragma unroll
  for (int c = 1; c < NCLS; ++c){ int v = counts[m*NCLS+c]; if (v > bc){ bc = v; best = c; } }
  spLabel[m] = best;

  __shared__ int waveCnt[16][NCLS];
  __shared__ int waveOff[16][NCLS];
  __shared__ int classTot[NCLS];
  __shared__ int classBase[NCLS];
  int lane = m & 63, wid = m >> 6;
  int nw = blockDim.x >> 6;
  int rankInWave = 0;
  unsigned long long below = (1ull << lane) - 1ull;
  for (int c = 0; c < NCLS; ++c){
    unsigned long long bal = __ballot(best == c);
    if (best == c) rankInWave = __popcll(bal & below);
    if (lane == 0) waveCnt[wid][c] = __popcll(bal);
  }
  __syncthreads();
  if (m < NCLS){
    int c = m, s = 0;
    for (int w = 0; w < nw; ++w){ waveOff[w][c] = s; s += waveCnt[w][c]; }
    classTot[c] = s;
  }
  __syncthreads();
  if (m == 0){ int s = 0; for (int c = 0; c < NCLS; ++c){ classBase[c] = s; s += classTot[c]; } }
  __syncthreads();
  int pos = classBase[best] + waveOff[wid][best] + rankInWave;
  newpos[m] = pos;
  atomicOr(&packLab[(pos >> 6)*16 + (pos & 15)], (unsigned)best << (((pos >> 4) & 3)*4));
}

// one wave per superpoint row: normalize; write spnO (bf16, linear, for pos logits)
// and spnP8 (fp8 e4m3, label-permuted row, K-INTERLEAVED layout for MFMA b128 reads):
// byte pos(k) = (k>>6)*64 + ((k>>3)&3)*16 + ((k>>5)&1)*8 + (k&7)
__global__ void k_norm_sp(const float* __restrict__ sp, const int* __restrict__ newpos,
                          unsigned short* __restrict__ spnO, unsigned char* __restrict__ spnP8){
  int m = blockIdx.x, lane = threadIdx.x;
  const float4 v = *(const float4*)(sp + (size_t)m*DIM + lane*4);
  float ss = v.x*v.x + v.y*v.y + v.z*v.z + v.w*v.w;
  #pragma unroll
  for (int o = 1; o < 64; o <<= 1) ss += __shfl_xor(ss, o);
  float rn = 1.0f / sqrtf(ss + 1e-12f);
  uint2 w;
  w.x = f2bf(v.x*rn) | (f2bf(v.y*rn) << 16);
  w.y = f2bf(v.z*rn) | (f2bf(v.w*rn) << 16);
  *(uint2*)(spnO + (size_t)m*DIM + lane*4) = w;
  // fp8 interleaved: lane holds k = 4*lane .. +3 -> one dword
  unsigned pk = pk4fp8(v.x*rn, v.y*rn, v.z*rn, v.w*rn);
  int p = newpos[m];
  int dw = ((lane>>4)<<4) + (((lane>>1)&3)<<2) + (((lane>>3)&1)<<1) + (lane&1); // pos(4l)/4
  ((unsigned*)spnP8)[p*64 + dw] = pk;
}

// ---------------- main fused GEMM (fp8) ----------------
// 512 threads = 8 waves; wave owns 32 rows x all 1024 cols. BM=256, grid 512.
// A: fp8 in regs a[2][8] longs (32 VGPR) via LDS staging with fused normalize.
// B: fp8 LDS chunks of 128 cols x 256 B = 32 KB, double-buffered (64 KB, overlays
// the A staging region), counted vmcnt(4) + raw s_barrier, 8 chunks.
// fp8 halves LDS bytes AND read count vs R9's bf16; mfma_f32_16x16x32_fp8_fp8
// has identical shape/rate to the bf16 op. e4m3 error ~2e-4 on the final scalar
// (70x under threshold); positive-column fp8 error cancels in (sumT - sumO).

#define SBAR()   __builtin_amdgcn_s_barrier()
#define SFENCE() __builtin_amdgcn_sched_barrier(0)

__device__ __forceinline__ void stageB(const unsigned char* __restrict__ spnP8,
                                       void* buf, int c, int tid){
  const int wid = tid >> 6;
  #pragma unroll
  for (int i = 0; i < 4; ++i){
    const int d   = i*8192 + tid*16;      // linear dst byte in 32 KB chunk
    const int col = d >> 8;               // 256 B per column
    const int gp  = (d >> 4) & 15;        // granule within column
    const unsigned char* src = spnP8 + (size_t)(c*128 + col)*256 + ((gp ^ (col & 7)) << 4);
    char* dst = (char*)buf + i*8192 + wid*1024;   // wave-uniform; HW adds lane*16
    gload_lds16(src, dst);
  }
}

__attribute__((amdgpu_waves_per_eu(1, 4)))
__launch_bounds__(512)
__global__ void k_main(const float* __restrict__ rp, const int* __restrict__ rawIdx,
                       const unsigned short* __restrict__ spnO, const unsigned char* __restrict__ spnP8,
                       const unsigned* __restrict__ packLab, const int* __restrict__ spLabel,
                       double* __restrict__ accum, int M){
  __shared__ __align__(16) char AB[65536];   // A staging (32 KB) then B dbuf (2x32 KB)
  __shared__ float    posLt[256];
  __shared__ int      posLb[256];
  __shared__ unsigned cpLds[256];

  const int tid  = threadIdx.x;
  const int lane = tid & 63, wid = tid >> 6;
  const int l15  = lane & 15, l4 = lane >> 4;
  const int rowBlock = blockIdx.x * 256;

  if (tid < 256) cpLds[tid] = packLab[tid];
  if (lane < 32){                                 // wave-local rows' labels
    int r = wid*32 + lane;
    posLb[r] = spLabel[rawIdx[rowBlock + r]];
  }

  // ---- prologue: normalize 32 rows/wave -> fp8 LDS slots (wave-private), frags to regs ----
  // lane(l4, t=l15): row it*4+l4 of pass p, elems [t*16, +16)
  long a[2][8];
  char* Ast = AB;                                 // 128 slots x 256 B
  #pragma unroll
  for (int p = 0; p < 2; ++p){
    for (int it = 0; it < 4; ++it){
      const int rl   = p*16 + it*4 + l4;          // wave-local row
      const int t    = l15;
      const float* rpp = rp + (size_t)(rowBlock + wid*32 + rl)*DIM + t*16;
      const float4 v0 = *(const float4*)(rpp);
      const float4 v1 = *(const float4*)(rpp + 4);
      const float4 v2 = *(const float4*)(rpp + 8);
      const float4 v3 = *(const float4*)(rpp + 12);
      float ss = v0.x*v0.x + v0.y*v0.y + v0.z*v0.z + v0.w*v0.w
               + v1.x*v1.x + v1.y*v1.y + v1.z*v1.z + v1.w*v1.w
               + v2.x*v2.x + v2.y*v2.y + v2.z*v2.z + v2.w*v2.w
               + v3.x*v3.x + v3.y*v3.y + v3.z*v3.z + v3.w*v3.w;
      const int sidx = rawIdx[rowBlock + wid*32 + rl];
      const uint4 s0 = *(const uint4*)(spnO + (size_t)sidx*DIM + t*16);
      const uint4 s1 = *(const uint4*)(spnO + (size_t)sidx*DIM + t*16 + 8);
      float dr =
        v0.x*bf2f(s0.x & 0xffff) + v0.y*bf2f(s0.x >> 16) +
        v0.z*bf2f(s0.y & 0xffff) + v0.w*bf2f(s0.y >> 16) +
        v1.x*bf2f(s0.z & 0xffff) + v1.y*bf2f(s0.z >> 16) +
        v1.z*bf2f(s0.w & 0xffff) + v1.w*bf2f(s0.w >> 16) +
        v2.x*bf2f(s1.x & 0xffff) + v2.y*bf2f(s1.x >> 16) +
        v2.z*bf2f(s1.y & 0xffff) + v2.w*bf2f(s1.y >> 16) +
        v3.x*bf2f(s1.z & 0xffff) + v3.y*bf2f(s1.z >> 16) +
        v3.z*bf2f(s1.w & 0xffff) + v3.w*bf2f(s1.w >> 16);
      ss += __shfl_xor(ss, 1); dr += __shfl_xor(dr, 1);
      ss += __shfl_xor(ss, 2); dr += __shfl_xor(dr, 2);
      ss += __shfl_xor(ss, 4); dr += __shfl_xor(dr, 4);
      ss += __shfl_xor(ss, 8); dr += __shfl_xor(dr, 8);
      const float rn = SCL / sqrtf(ss + 1e-12f);  // log2e/T folded into A
      // fp8 pack, K-interleaved store (wave-private slot)
      const int slot = wid*16 + it*4 + l4;
      const int swz  = (slot & 7) << 4;
      const int kpair = t >> 2, hlf = (t >> 1) & 1;
      char* sb = Ast + slot*256;
      uint2 h0, h1;
      h0.x = pk4fp8(v0.x*rn, v0.y*rn, v0.z*rn, v0.w*rn);
      h0.y = pk4fp8(v1.x*rn, v1.y*rn, v1.z*rn, v1.w*rn);
      h1.x = pk4fp8(v2.x*rn, v2.y*rn, v2.z*rn, v2.w*rn);
      h1.y = pk4fp8(v3.x*rn, v3.y*rn, v3.z*rn, v3.w*rn);
      const int l4f0 = (2*t)     & 3;
      const int l4f1 = (2*t + 1) & 3;
      *(uint2*)(sb + ((kpair*64 + l4f0*16 + hlf*8) ^ swz)) = h0;
      *(uint2*)(sb + ((kpair*64 + l4f1*16 + hlf*8) ^ swz)) = h1;
      if (l15 == 0) posLt[wid*32 + rl] = rn * dr;
    }
    // frag reads: slot rows written by THIS wave (same-wave LDS ordering)
    #pragma unroll
    for (int kp = 0; kp < 4; ++kp){
      const int s = wid*16 + l15;
      uint4 q = *(const uint4*)(Ast + s*256 + ((kp*64 + l4*16) ^ ((l15 & 7) << 4)));
      a[p][2*kp]   = (long)((((unsigned long long)q.y) << 32) | q.x);
      a[p][2*kp+1] = (long)((((unsigned long long)q.w) << 32) | q.z);
    }
  }

  // row labels nibble-packed: ri = rt*4+e -> wave-local row rt*16 + l4*4 + e
  unsigned Lpack = 0;
  #pragma unroll
  for (int rt = 0; rt < 2; ++rt)
    #pragma unroll
    for (int e = 0; e < 4; ++e)
      Lpack |= ((unsigned)posLb[wid*32 + rt*16 + l4*4 + e]) << ((rt*4 + e)*4);

  float sumT[8], sumO[8];
  #pragma unroll
  for (int i = 0; i < 8; ++i){ sumT[i] = 0.f; sumO[i] = 0.f; }

  __syncthreads();   // all waves done with Ast; AB becomes B double-buffer

  stageB(spnP8, AB,         0, tid);   // chunk 0
  stageB(spnP8, AB + 32768, 1, tid);   // chunk 1 (depth-2)

  const int nChunks = M >> 7;          // 8 chunks of 128 cols
  for (int c = 0; c < nChunks; ++c){
    if (c < nChunks - 1) asm volatile("s_waitcnt vmcnt(4)" ::: "memory");
    else                 asm volatile("s_waitcnt vmcnt(0)" ::: "memory");
    SFENCE(); SBAR(); SFENCE();

    const char* Bp = AB + (c & 1)*32768;
    #pragma unroll
    for (int cf = 0; cf < 8; ++cf){
      const int colp = cf*16 + l15;
      const int swz  = (l15 & 7) << 4;
      long b[8];
      #pragma unroll
      for (int kp = 0; kp < 4; ++kp){
        uint4 q = *(const uint4*)(Bp + colp*256 + ((kp*64 + l4*16) ^ swz));
        b[2*kp]   = (long)((((unsigned long long)q.y) << 32) | q.x);
        b[2*kp+1] = (long)((((unsigned long long)q.w) << 32) | q.z);
      }
      f32x4 acc0 = (f32x4){0.f,0.f,0.f,0.f};
      f32x4 acc1 = (f32x4){0.f,0.f,0.f,0.f};
      #pragma unroll
      for (int kq = 0; kq < 8; ++kq){
        acc0 = __builtin_amdgcn_mfma_f32_16x16x32_fp8_fp8(a[0][kq], b[kq], acc0, 0, 0, 0);
        acc1 = __builtin_amdgcn_mfma_f32_16x16x32_fp8_fp8(a[1][kq], b[kq], acc1, 0, 0, 0);
      }
      const unsigned cpack  = cpLds[(c*2 + (cf >> 2))*16 + l15];
      const unsigned colLab = (cpack >> ((cf & 3)*4)) & 15u;
      #pragma unroll
      for (int e = 0; e < 4; ++e){
        const float ev0 = __builtin_amdgcn_exp2f(acc0[e]);
        const float ev1 = __builtin_amdgcn_exp2f(acc1[e]);
        sumT[e]   += ev0;
        sumT[4+e] += ev1;
        sumO[e]   += (((Lpack >> (e*4)) & 15u)     == colLab) ? ev0 : 0.f;
        sumO[4+e] += (((Lpack >> ((4+e)*4)) & 15u) == colLab) ? ev1 : 0.f;
      }
    }
    SFENCE(); SBAR(); SFENCE();
    if (c + 2 < nChunks) stageB(spnP8, AB + (c & 1)*32768, c + 2, tid);
  }

  // reduce over the 16 l15-lanes sharing each row
  #pragma unroll
  for (int i = 0; i < 8; ++i){
    #pragma unroll
    for (int o = 1; o < 16; o <<= 1){
      sumT[i] += __shfl_xor(sumT[i], o);
      sumO[i] += __shfl_xor(sumO[i], o);
    }
  }

  // finish in log2 domain: loss_i = ln2 * (log2(den) - pl2); ln2 folded into k_final
  float part = 0.f;
  #pragma unroll
  for (int rt = 0; rt < 2; ++rt)
    #pragma unroll
    for (int e = 0; e < 4; ++e){
      const float pl  = posLt[wid*32 + rt*16 + l4*4 + e];
      const float ep  = __builtin_amdgcn_exp2f(pl);
      const float den = ep + (sumT[rt*4+e] - sumO[rt*4+e]) + 1e-8f;
      part += __builtin_amdgcn_logf(den) - pl;   // v_log_f32 = log2
    }
  part = (l15 == 0) ? part : 0.f;
  #pragma unroll
  for (int o = 1; o < 64; o <<= 1) part += __shfl_xor(part, o);
  if (lane == 0) atomicAdd(accum, (double)part);
}

__global__ void k_final(const double* __restrict__ accum, float* __restrict__ out, int N){
  out[0] = (float)((*accum / (double)N) * (0.07 * 0.6931471805599453));
}

// ---------------- launch ----------------

extern "C" void kernel_launch(void* const* d_in, const int* in_sizes, int n_in,
                              void* d_out, int out_size, void* d_ws, size_t ws_size,
                              hipStream_t stream){
  const float* sp  = (const float*)d_in[0];
  const float* rp  = (const float*)d_in[1];
  const int*   idx = (const int*)d_in[2];
  const int*   lab = (const int*)d_in[3];
  const int M = in_sizes[0] / DIM;     // 1024
  const int N = in_sizes[2];           // 131072

  char* ws = (char*)d_ws;
  size_t off = 0;
  auto alloc = [&](size_t bytes){ void* p = ws + off; off = (off + bytes + 255) & ~(size_t)255; return p; };
  int*      counts  = (int*)     alloc((size_t)M * NCLS * 4);
  int*      spLabel = (int*)     alloc((size_t)M * 4);
  int*      newpos  = (int*)     alloc((size_t)M * 4);
  unsigned* packLab = (unsigned*)alloc((size_t)(M/64) * 16 * 4);
  double*   accum   = (double*)  alloc(16);
  unsigned short* spnO = (unsigned short*)alloc((size_t)M * DIM * 2);
  unsigned char*  spnP8 = (unsigned char*)alloc((size_t)M * DIM);

  k_zero<<<(M*NCLS + 255)/256, 256, 0, stream>>>(counts, packLab, accum, M*NCLS, (M/64)*16);
  k_hist<<<(N + 255)/256, 256, 0, stream>>>(idx, lab, counts, N);
  k_label_perm<<<1, M, 0, stream>>>(counts, spLabel, newpos, packLab);
  k_norm_sp<<<M, 64, 0, stream>>>(sp, newpos, spnO, spnP8);
  k_main<<<N/256, 512, 0, stream>>>(rp, idx, spnO, spnP8, packLab, spLabel, accum, M);
  k_final<<<1, 1, 0, stream>>>(accum, (float*)d_out, N);
}